// Round 11
// baseline (4075.452 us; speedup 1.0000x reference)
//
#include <hip/hip_runtime.h>
#include <hip/hip_bf16.h>
#include <stdint.h>

// TextRNN: 2-layer tanh RNN. B=128,T=512,H=512,E=256,V=32000.
// R11 = R7 skeleton (proven correct end-to-end in slow mode) + co-XCD L2 fast path
//   done right: fast mode uses sc0 stores/loads with `buffer_inv` (L1 invalidate)
//   before every poll retry — the same invalidate the R2 compiler-emitted acquire
//   path used (proven to exist & work on gfx950). Probe verifies THIS mechanism
//   (2 rounds, catches stale-L1) and falls back to the proven sc0sc1 MALL protocol.
//   s_sleep(1) restored in all poll loops (R7's unthrottled polls congested MALL).
// R8-R10 post-mortem: tagged-slot design NaN'd twice for causes not statically
//   identifiable -> abandoned per rigor rules. Back to proven barrier protocol.

#define VOCAB 32000
#define EMB   256
#define HID   512
#define SEQ   512
#define SLOT  8192          // one time-slot: 8 members * 1024 shorts ([oct][row][k&7])
#define NSLOT 4

typedef __attribute__((ext_vector_type(8))) short bf16x8;
typedef __attribute__((ext_vector_type(4))) float f32x4;

__device__ inline short f2bf(float f) {
  union { float f; uint32_t u; } v; v.f = f;
  uint32_t u = v.u;
  uint32_t r = (u + 0x7FFFu + ((u >> 16) & 1u)) >> 16;
  return (short)r;
}
__device__ inline float bf2f(unsigned short s) {
  union { uint32_t u; float f; } v; v.u = ((uint32_t)s) << 16;
  return v.f;
}
__device__ inline bf16x8 cvt8(f32x4 x0, f32x4 x1) {
  bf16x8 r;
  r[0]=f2bf(x0[0]); r[1]=f2bf(x0[1]); r[2]=f2bf(x0[2]); r[3]=f2bf(x0[3]);
  r[4]=f2bf(x1[0]); r[5]=f2bf(x1[1]); r[6]=f2bf(x1[2]); r[7]=f2bf(x1[3]);
  return r;
}
__device__ inline f32x4 mfma16(bf16x8 a, bf16x8 b, f32x4 c) {
  return __builtin_amdgcn_mfma_f32_16x16x32_bf16(a, b, c, 0, 0, 0);
}
__device__ inline float fast_tanh(float x) {
  x = fminf(30.f, fmaxf(-30.f, x));
  float e = __expf(2.f * x);
  return (e - 1.f) * __builtin_amdgcn_rcpf(e + 1.f);
}

#define VMCNT0  asm volatile("s_waitcnt vmcnt(0)" ::: "memory")
#define VMCNT16 asm volatile("s_waitcnt vmcnt(16)" ::: "memory")
#define LGKM0   asm volatile("s_waitcnt lgkmcnt(0)" ::: "memory")
#define SCHED0  __builtin_amdgcn_sched_barrier(0)

// ---- dual-path primitives ----------------------------------------------------
template <bool FAST>
__device__ inline void stq(unsigned short* p, bf16x8 v) {
  if (FAST) asm volatile("global_store_dwordx4 %0, %1, off sc0"     :: "v"(p), "v"(v) : "memory");
  else      asm volatile("global_store_dwordx4 %0, %1, off sc0 sc1" :: "v"(p), "v"(v) : "memory");
}
template <bool FAST>
__device__ inline void sigst(unsigned* p, unsigned v) {
  if (FAST) asm volatile("global_store_dword %0, %1, off sc0"     :: "v"(p), "v"(v) : "memory");
  else      asm volatile("global_store_dword %0, %1, off sc0 sc1" :: "v"(p), "v"(v) : "memory");
}
// poll flag load: fast = L1-invalidate + sc0 (served by XCD L2, never stale-L1)
template <bool FAST>
__device__ inline unsigned ldf(const unsigned* p) {
  unsigned v;
  if (FAST) asm volatile("buffer_inv\n\tglobal_load_dword %0, %1, off sc0\n\ts_waitcnt vmcnt(0)"
                         : "=v"(v) : "v"(p) : "memory");
  else      asm volatile("global_load_dword %0, %1, off sc0 sc1\n\ts_waitcnt vmcnt(0)"
                         : "=v"(v) : "v"(p) : "memory");
  return v;
}
// data volley: fast = sc0 (caller guarantees a buffer_inv happened after flag-pass)
template <bool FAST>
__device__ inline void load16(bf16x8* arr, const char* base) {
#pragma unroll
  for (int s = 0; s < 16; ++s) {
    if (FAST) asm volatile("global_load_dwordx4 %0, %1, off sc0"
                           : "=v"(arr[s]) : "v"(base + s * 1024) : "memory");
    else      asm volatile("global_load_dwordx4 %0, %1, off sc0 sc1"
                           : "=v"(arr[s]) : "v"(base + s * 1024) : "memory");
  }
}
// lanes 0-15: f0[lane] >= t0 ; lanes 16-31: f1[lane-16] >= t1 ; others idle
template <bool FAST>
__device__ inline void poll2(const unsigned* f0, const unsigned* f1,
                             unsigned t0, unsigned t1) {
  const int lane = threadIdx.x & 63;
  bool ok = (lane >= 32);
  const unsigned* fp = (lane < 16) ? (f0 + lane) : (f1 + (lane - 16));
  const unsigned tgt = (lane < 16) ? t0 : t1;
  int guard = 0;
  while (__ballot(ok) != ~0ull) {
    if (!ok) ok = (ldf<FAST>(fp) >= tgt);
    if (__ballot(ok) == ~0ull) break;
    __builtin_amdgcn_s_sleep(1);
    if (++guard > 30000) break;   // fail visibly, never hang the harness
  }
}

__global__ void k_init(unsigned* __restrict__ p, int n) {
  int i = blockIdx.x * 256 + threadIdx.x;
  if (i < n) p[i] = 0u;
}

// ---- CW = C @ W_ax.T  (M=32000, N=512, K=256), bf16 out ----
__global__ void __launch_bounds__(256) k_cw(const float* __restrict__ C,
                                            const float* __restrict__ Wax,
                                            unsigned short* __restrict__ CW) {
  const int tid = threadIdx.x, lane = tid & 63, wv = tid >> 6;
  const int l15 = lane & 15, l4 = lane >> 4;
  const int row = blockIdx.x * 64 + wv * 16 + l15;
  bf16x8 a[8];
  const float* crow = C + (size_t)row * EMB;
#pragma unroll
  for (int s = 0; s < 8; ++s) {
    const f32x4* p = (const f32x4*)(crow + s * 32 + l4 * 8);
    a[s] = cvt8(p[0], p[1]);
  }
  const int row_o_base = blockIdx.x * 64 + wv * 16 + l4 * 4;
  for (int ct = 0; ct < 8; ++ct) {
    f32x4 acc[4];
#pragma unroll
    for (int nf = 0; nf < 4; ++nf) acc[nf] = (f32x4){0.f, 0.f, 0.f, 0.f};
#pragma unroll
    for (int s = 0; s < 8; ++s) {
#pragma unroll
      for (int nf = 0; nf < 4; ++nf) {
        int col = ct * 64 + nf * 16 + l15;
        const f32x4* bp = (const f32x4*)(Wax + (size_t)col * EMB + s * 32 + l4 * 8);
        bf16x8 b = cvt8(bp[0], bp[1]);
        acc[nf] = mfma16(a[s], b, acc[nf]);
      }
    }
#pragma unroll
    for (int nf = 0; nf < 4; ++nf) {
      int col = ct * 64 + nf * 16 + l15;
#pragma unroll
      for (int r = 0; r < 4; ++r)
        CW[(size_t)(row_o_base + r) * HID + col] = (unsigned short)f2bf(acc[nf][r]);
    }
  }
}

// ---- scan main loop (templated on protocol) ----
template <bool FAST>
__device__ __forceinline__ void scan_run(
    const int* __restrict__ X, const unsigned short* __restrict__ CW,
    unsigned short* __restrict__ h0g, unsigned short* __restrict__ h1g,
    unsigned* __restrict__ f0, unsigned* __restrict__ f1,
    const unsigned short* ldsWaa, const unsigned short* ldsWal, unsigned short* pk,
    int jc0, int jc1, float ba0, float ba1, int wb0, int wb1, int swz,
    int aoff, int pl0, int pl1, int stbase, int brow, int mem, int wv, int lane) {
  const int l4 = lane >> 4;
#define WFRAG(W, wb, s) (*(const bf16x8*)((W) + (wb) + ((((s) * 4 + l4) ^ swz) * 8)))
  if (wv < 2) {
    // ================= h0 producers (waves 0,1) =================
    unsigned* myf = f0 + 2 * mem + (wv & 1);
    int idxA[4];
    unsigned cw0[4], cw1[4];
    { // prologue: idx(0) -> cw(0) gathers; then idx(1)
      int id0[4];
#pragma unroll
      for (int r = 0; r < 4; ++r)
        asm volatile("global_load_dword %0, %1, off"
                     : "=v"(id0[r]) : "v"(X + (size_t)(brow + r) * SEQ) : "memory");
      VMCNT0; SCHED0;
#pragma unroll
      for (int r = 0; r < 4; ++r) {
        const unsigned short* c0 = CW + (size_t)id0[r] * HID + jc0;
        asm volatile("global_load_ushort %0, %1, off" : "=v"(cw0[r]) : "v"(c0) : "memory");
        asm volatile("global_load_ushort %0, %1, off" : "=v"(cw1[r]) : "v"(c0 + 16) : "memory");
      }
#pragma unroll
      for (int r = 0; r < 4; ++r)
        asm volatile("global_load_dword %0, %1, off"
                     : "=v"(idxA[r]) : "v"(X + (size_t)(brow + r) * SEQ + 1) : "memory");
    }
    for (int t = 0; t < SEQ; ++t) {
      poll2<FAST>(f0, f1, (unsigned)t, (unsigned)(t >= 2 ? t - 2 : 0));
      bf16x8 a0[16];
      const char* pa0 = (const char*)(h0g + ((t + 3) & 3) * SLOT + aoff);
      load16<FAST>(a0, pa0);
      VMCNT0; SCHED0;
      f32x4 acc0 = (f32x4){0.f, 0.f, 0.f, 0.f};
      f32x4 acc1 = (f32x4){0.f, 0.f, 0.f, 0.f};
#pragma unroll
      for (int s = 0; s < 16; ++s) {
        bf16x8 a = a0[s];
        acc0 = mfma16(a, WFRAG(ldsWaa, wb0, s), acc0);
        acc1 = mfma16(a, WFRAG(ldsWaa, wb1, s), acc1);
      }
#pragma unroll
      for (int r = 0; r < 4; ++r) {
        float v0 = fast_tanh(acc0[r] + bf2f((unsigned short)cw0[r]) + ba0);
        float v1 = fast_tanh(acc1[r] + bf2f((unsigned short)cw1[r]) + ba1);
        pk[pl0 + r * 8] = (unsigned short)f2bf(v0);
        pk[pl1 + r * 8] = (unsigned short)f2bf(v1);
      }
      LGKM0; SCHED0;                       // wave-private pack complete
      bf16x8 ov = *(const bf16x8*)(pk + lane * 8);
      stq<FAST>(h0g + (t & 3) * SLOT + stbase, ov);
      VMCNT0;                              // store at coherent point (L2 fast / MALL slow)
      if (lane == 0) sigst<FAST>(myf, (unsigned)(t + 1));
      // tail prefetches: cw(t+1) via idxA (=X(t+1), drained), then idxA <- X(t+2)
#pragma unroll
      for (int r = 0; r < 4; ++r) {
        const unsigned short* c0 = CW + (size_t)idxA[r] * HID + jc0;
        asm volatile("global_load_ushort %0, %1, off" : "=v"(cw0[r]) : "v"(c0) : "memory");
        asm volatile("global_load_ushort %0, %1, off" : "=v"(cw1[r]) : "v"(c0 + 16) : "memory");
      }
      const int tp = (t + 2 < SEQ) ? t + 2 : SEQ - 1;
#pragma unroll
      for (int r = 0; r < 4; ++r)
        asm volatile("global_load_dword %0, %1, off"
                     : "=v"(idxA[r]) : "v"(X + (size_t)(brow + r) * SEQ + tp) : "memory");
    }
  } else {
    // ================= h1 producers (waves 2,3): step t computes h1(t-1) =========
    unsigned* myf = f1 + 2 * mem + (wv & 1);
    for (int t = 0; t <= SEQ; ++t) {
      poll2<FAST>(f0, f1, (unsigned)t, (unsigned)t);
      if (t >= 1) {
        bf16x8 a1[16], a2[16];
        const char* pa1 = (const char*)(h0g + ((t + 3) & 3) * SLOT + aoff);  // h0(t-1)
        const char* pa2 = (const char*)(h1g + ((t + 2) & 3) * SLOT + aoff);  // h1(t-2)
        load16<FAST>(a1, pa1);
        load16<FAST>(a2, pa2);
        VMCNT16; SCHED0;                   // a1 ready
        f32x4 acc0 = (f32x4){0.f, 0.f, 0.f, 0.f};
        f32x4 acc1 = (f32x4){0.f, 0.f, 0.f, 0.f};
#pragma unroll
        for (int s = 0; s < 16; ++s) {
          bf16x8 a = a1[s];
          acc0 = mfma16(a, WFRAG(ldsWal, wb0, s), acc0);
          acc1 = mfma16(a, WFRAG(ldsWal, wb1, s), acc1);
        }
        VMCNT0; SCHED0;                    // a2 ready
#pragma unroll
        for (int s = 0; s < 16; ++s) {
          bf16x8 a = a2[s];
          acc0 = mfma16(a, WFRAG(ldsWaa, wb0, s), acc0);
          acc1 = mfma16(a, WFRAG(ldsWaa, wb1, s), acc1);
        }
#pragma unroll
        for (int r = 0; r < 4; ++r) {
          float v0 = fast_tanh(acc0[r] + ba0);
          float v1 = fast_tanh(acc1[r] + ba1);
          pk[pl0 + r * 8] = (unsigned short)f2bf(v0);
          pk[pl1 + r * 8] = (unsigned short)f2bf(v1);
        }
        LGKM0; SCHED0;
        bf16x8 ov = *(const bf16x8*)(pk + lane * 8);
        stq<FAST>(h1g + ((t + 3) & 3) * SLOT + stbase, ov);  // h1(t-1) -> slot (t-1)%4
        VMCNT0;
      }
      if (lane == 0) sigst<FAST>(myf, (unsigned)(t + 1));
    }
  }
#undef WFRAG
}

// ---- the recurrent scan ----
__global__ void __launch_bounds__(256, 1) k_scan(
    const int* __restrict__ X, const float* __restrict__ Waa, const float* __restrict__ Wal,
    const float* __restrict__ ba, const unsigned short* __restrict__ CW,
    unsigned short* __restrict__ h0buf, unsigned short* __restrict__ h1buf,
    unsigned* __restrict__ flags) {
  extern __shared__ unsigned short lds[];
  unsigned short* ldsWaa = lds;                 // [64][512] bf16, 16B-unit swizzled
  unsigned short* ldsWal = lds + 64 * 512;
  unsigned short* packb  = lds + 2 * 64 * 512;  // 4 waves x 512 shorts (private)
  __shared__ unsigned s_mode;
  const int tid = threadIdx.x, lane = tid & 63, wv = tid >> 6;
  const int l15 = lane & 15, l4 = lane >> 4;
  const int g = blockIdx.x & 7, mem = blockIdx.x >> 3;
  const int colslice = mem * 64;
  unsigned* fl = flags + g * 64;
  unsigned* f0 = fl;            // 16 flags: h0 (2 per member)
  unsigned* f1 = fl + 16;       // 16 flags: h1
  unsigned* pp = fl + 32;       // 8: probe posts (MALL atomics)
  unsigned* pv = fl + 40;       // 8: probe verdicts (MALL)
  unsigned* pd = flags + 512 + g * 32;  // probe data: isolated 128B line per group

  // stage weight slices f32 -> bf16 LDS, 16B-unit swizzled
  for (int c = tid; c < 64 * 64; c += 256) {
    int row = c >> 6, u = c & 63, us = u ^ (row & 7);
    {
      const f32x4* p = (const f32x4*)(Waa + (size_t)(colslice + row) * HID + u * 8);
      *(bf16x8*)(ldsWaa + row * 512 + us * 8) = cvt8(p[0], p[1]);
    }
    {
      const f32x4* p = (const f32x4*)(Wal + (size_t)(colslice + row) * HID + u * 8);
      *(bf16x8*)(ldsWal + row * 512 + us * 8) = cvt8(p[0], p[1]);
    }
  }

  // ---- coherence probe (wave 0): do sc0 stores + buffer_inv + sc0 loads give
  //      cross-member visibility (shared XCD L2)? 2 rounds; round 2 catches staleness.
  if (wv == 0) {
    const unsigned MAG1 = 0x5EED0000u + (unsigned)(g << 8);
    const unsigned MAG2 = 0x7EED0000u + (unsigned)(g << 8);
    bool okm = true;
    // round 1
    if (lane == 0) {
      asm volatile("global_store_dword %0, %1, off sc0"
                   :: "v"(pd + mem), "v"(MAG1 + (unsigned)mem) : "memory");
      VMCNT0;
      __hip_atomic_store(pp + mem, 1u, __ATOMIC_RELAXED, __HIP_MEMORY_SCOPE_AGENT);
    }
    { bool ok = (lane >= 8); int gd = 0;
      while (__ballot(ok) != ~0ull) {
        if (!ok) ok = (ldf<false>(pp + (lane & 7)) >= 1u);
        __builtin_amdgcn_s_sleep(1);
        if (++gd > 300000) break; } }
    if (lane < 8) okm = (ldf<true>(pd + lane) == MAG1 + (unsigned)lane);
    // round 2 (staleness test: same words, new values)
    if (lane == 0) {
      asm volatile("global_store_dword %0, %1, off sc0"
                   :: "v"(pd + mem), "v"(MAG2 + (unsigned)mem) : "memory");
      VMCNT0;
      __hip_atomic_store(pp + mem, 2u, __ATOMIC_RELAXED, __HIP_MEMORY_SCOPE_AGENT);
    }
    { bool ok = (lane >= 8); int gd = 0;
      while (__ballot(ok) != ~0ull) {
        if (!ok) ok = (ldf<false>(pp + (lane & 7)) >= 2u);
        __builtin_amdgcn_s_sleep(1);
        if (++gd > 300000) break; } }
    if (lane < 8) okm = okm && (ldf<true>(pd + lane) == MAG2 + (unsigned)lane);
    bool myv = (__ballot(okm) == ~0ull);
    if (lane == 0)
      asm volatile("global_store_dword %0, %1, off sc0 sc1"
                   :: "v"(pv + mem), "v"(myv ? 1u : 2u) : "memory");
    { bool ok = (lane >= 8); unsigned vv = 1u; int gd = 0;
      while (__ballot(ok) != ~0ull) {
        if (!ok) { vv = ldf<false>(pv + (lane & 7)); ok = (vv != 0u); }
        __builtin_amdgcn_s_sleep(1);
        if (++gd > 300000) break; }
      bool f = (lane >= 8) || (vv == 1u);
      if (lane == 0) s_mode = (__ballot(f) == ~0ull) ? 1u : 0u; }
  }
  __syncthreads();
  const bool fastmode = (s_mode != 0u);

  // per-wave geometry: each wave owns 2 col-tiles (32 cols)
  const int cb  = (wv & 1) * 2;                  // col-tile base within slice
  const int jc0 = colslice + cb * 16 + l15;      // out col, chain 0
  const int jc1 = jc0 + 16;                      // out col, chain 1
  const float ba0 = ba[jc0], ba1 = ba[jc1];
  const int wb0 = (cb * 16 + l15) * 512;         // LDS weight row base
  const int wb1 = wb0 + 16 * 512;
  const int swz = l15 & 7;
  const int aoff = l4 * 128 + l15 * 8;           // A-frag lane offset (shorts)
  unsigned short* pk = packb + wv * 512;
  const int pl0 = ((l15 >> 3) + 0) * 128 + (l4 * 4) * 8 + (l15 & 7);
  const int pl1 = ((l15 >> 3) + 2) * 128 + (l4 * 4) * 8 + (l15 & 7);
  const int stbase = mem * 1024 + cb * 256 + lane * 8;  // wave's contiguous 1KB region
  const int brow = g * 16 + l4 * 4;
  unsigned short* h0g = h0buf + (size_t)g * (NSLOT * SLOT);
  unsigned short* h1g = h1buf + (size_t)g * (NSLOT * SLOT);

  if (fastmode)
    scan_run<true>(X, CW, h0g, h1g, f0, f1, ldsWaa, ldsWal, pk,
                   jc0, jc1, ba0, ba1, wb0, wb1, swz, aoff, pl0, pl1,
                   stbase, brow, mem, wv, lane);
  else
    scan_run<false>(X, CW, h0g, h1g, f0, f1, ldsWaa, ldsWal, pk,
                    jc0, jc1, ba0, ba1, wb0, wb1, swz, aoff, pl0, pl1,
                    stbase, brow, mem, wv, lane);
}

// ---- out = h1_final @ W_out.T + b_out  (M=128, N=32000, K=512) ----
__global__ void __launch_bounds__(256) k_out(const float* __restrict__ Wout,
                                             const float* __restrict__ bout,
                                             const unsigned short* __restrict__ h1buf,
                                             float* __restrict__ out) {
  const int tid = threadIdx.x, lane = tid & 63, wv = tid >> 6;
  const int l15 = lane & 15, l4 = lane >> 4;
  const int col = blockIdx.x * 64 + wv * 16 + l15;
  const float bo = bout[col];
  f32x4 acc[8];
#pragma unroll
  for (int rt = 0; rt < 8; ++rt) acc[rt] = (f32x4){0.f, 0.f, 0.f, 0.f};
  const int aoff = l4 * 128 + l15 * 8;
#pragma unroll 4
  for (int s = 0; s < 16; ++s) {
    const f32x4* bp = (const f32x4*)(Wout + (size_t)col * HID + s * 32 + l4 * 8);
    bf16x8 b = cvt8(bp[0], bp[1]);
#pragma unroll
    for (int rt = 0; rt < 8; ++rt) {
      // group rt, slot 3 (= 511 & 3) holds final h1(511)
      const unsigned short* ap = h1buf + (size_t)rt * (NSLOT * SLOT) + 3 * SLOT + aoff + s * 512;
      acc[rt] = mfma16(*(const bf16x8*)ap, b, acc[rt]);
    }
  }
#pragma unroll
  for (int rt = 0; rt < 8; ++rt) {
#pragma unroll
    for (int r = 0; r < 4; ++r) {
      int row = rt * 16 + l4 * 4 + r;
      out[(size_t)row * VOCAB + col] = acc[rt][r] + bo;
    }
  }
}

extern "C" void kernel_launch(void* const* d_in, const int* in_sizes, int n_in,
                              void* d_out, int out_size, void* d_ws, size_t ws_size,
                              hipStream_t stream) {
  const int*   X    = (const int*)d_in[0];
  const float* C    = (const float*)d_in[1];
  const float* Wax  = (const float*)d_in[2];
  const float* Waa  = (const float*)d_in[3];
  const float* Wal  = (const float*)d_in[4];
  const float* ba   = (const float*)d_in[5];
  const float* Wout = (const float*)d_in[6];
  const float* bout = (const float*)d_in[7];
  float* out = (float*)d_out;
  char* ws = (char*)d_ws;
  (void)in_sizes; (void)n_in; (void)out_size;

  const size_t cw_bytes = (size_t)VOCAB * HID * 2;   // 32,768,000
  const size_t h_bytes  = 8ull * NSLOT * SLOT * 2;   // 524,288 per tensor
  const size_t off_h0 = cw_bytes;
  const size_t off_h1 = off_h0 + h_bytes;
  const size_t off_fl = off_h1 + h_bytes;
  const size_t fl_bytes = 2048 + 1024;               // flags (8x64W) + pd lines
  if (ws_size < off_fl + fl_bytes) return;           // visible failure

  unsigned short* CWp = (unsigned short*)ws;
  unsigned short* h0  = (unsigned short*)(ws + off_h0);
  unsigned short* h1  = (unsigned short*)(ws + off_h1);
  unsigned*       fl  = (unsigned*)(ws + off_fl);

  const int zero_words = (int)((2 * h_bytes + fl_bytes) / 4);
  hipLaunchKernelGGL(k_init, dim3((zero_words + 255) / 256), dim3(256), 0, stream,
                     (unsigned*)(ws + off_h0), zero_words);
  hipLaunchKernelGGL(k_cw, dim3(VOCAB / 64), dim3(256), 0, stream, C, Wax, CWp);
  hipFuncSetAttribute((const void*)k_scan, hipFuncAttributeMaxDynamicSharedMemorySize, 135168);
  hipLaunchKernelGGL(k_scan, dim3(64), dim3(256), 135168, stream,
                     X, Waa, Wal, ba, CWp, h0, h1, fl);
  hipLaunchKernelGGL(k_out, dim3(VOCAB / 64), dim3(256), 0, stream, Wout, bout, h1, out);
}

// Round 12
// 2312.100 us; speedup vs baseline: 1.7627x; 1.7627x over previous
//
#include <hip/hip_runtime.h>
#include <hip/hip_bf16.h>
#include <stdint.h>

// TextRNN: 2-layer tanh RNN. B=128,T=512,H=512,E=256,V=32000.
// R12 = exact R6 source (proven 1950us) + poll-prefetch: producers pre-issue next
//   step's flag loads at the loop tail; loop-top VMCNT0+SCHED0 drains them; lanes
//   whose pre-read passes skip the retry loop. Hides one MALL RTT per step.
// R11 post-mortem: honest probe rejected sc0+buffer_inv visibility -> %8 co-XCD
//   grouping assumption is wrong here; L2 fast path abandoned for good. R7/R11's
//   2x-vs-R6 regression tracked to the probe/template restructuring -> reverted to
//   R6 verbatim as the base.

#define VOCAB 32000
#define EMB   256
#define HID   512
#define BATCH 128
#define SEQ   512
#define SLOT  8192          // one time-slot: 64 units * 16 rows * 8 shorts
#define NSLOT 4

typedef __attribute__((ext_vector_type(8))) short bf16x8;
typedef __attribute__((ext_vector_type(4))) float f32x4;

__device__ inline short f2bf(float f) {
  union { float f; uint32_t u; } v; v.f = f;
  uint32_t u = v.u;
  uint32_t r = (u + 0x7FFFu + ((u >> 16) & 1u)) >> 16;
  return (short)r;
}
__device__ inline float bf2f(unsigned short s) {
  union { uint32_t u; float f; } v; v.u = ((uint32_t)s) << 16;
  return v.f;
}
__device__ inline bf16x8 cvt8(f32x4 x0, f32x4 x1) {
  bf16x8 r;
  r[0]=f2bf(x0[0]); r[1]=f2bf(x0[1]); r[2]=f2bf(x0[2]); r[3]=f2bf(x0[3]);
  r[4]=f2bf(x1[0]); r[5]=f2bf(x1[1]); r[6]=f2bf(x1[2]); r[7]=f2bf(x1[3]);
  return r;
}
__device__ inline f32x4 mfma16(bf16x8 a, bf16x8 b, f32x4 c) {
  return __builtin_amdgcn_mfma_f32_16x16x32_bf16(a, b, c, 0, 0, 0);
}
__device__ inline float fast_tanh(float x) {
  x = fminf(30.f, fmaxf(-30.f, x));
  float e = __expf(2.f * x);
  return (e - 1.f) * __builtin_amdgcn_rcpf(e + 1.f);
}

#define VMCNT0  asm volatile("s_waitcnt vmcnt(0)" ::: "memory")
#define VMCNT16 asm volatile("s_waitcnt vmcnt(16)" ::: "memory")
#define LGKM0   asm volatile("s_waitcnt lgkmcnt(0)" ::: "memory")
#define SCHED0  __builtin_amdgcn_sched_barrier(0)

__device__ inline void st16(unsigned short* p, bf16x8 v) {
  asm volatile("global_store_dwordx4 %0, %1, off sc0 sc1" :: "v"(p), "v"(v) : "memory");
}
__device__ inline void sig(unsigned* p, unsigned v) {
  asm volatile("global_store_dword %0, %1, off sc0 sc1" :: "v"(p), "v"(v) : "memory");
}
// lanes 0-15: f0[lane] >= t0 ; lanes 16-31: f1[lane-16] >= t1 ; others idle.
// pre = pre-issued flag value (drained by caller's VMCNT0;SCHED0 before this call):
// lanes whose pre already satisfies the target skip the reload loop entirely.
__device__ inline void poll2p(const unsigned* f0, const unsigned* f1,
                              unsigned t0, unsigned t1, unsigned pre) {
  const int lane = threadIdx.x & 63;
  const unsigned* fp = (lane < 16) ? (f0 + lane) : (f1 + (lane - 16));
  const unsigned tgt = (lane < 16) ? t0 : t1;
  bool ok = (lane >= 32) || (pre >= tgt);
  unsigned v = 0; int guard = 0;
  while (__ballot(ok) != ~0ull) {
    if (!ok) {
      asm volatile("global_load_dword %0, %1, off sc0 sc1\n\ts_waitcnt vmcnt(0)"
                   : "=v"(v) : "v"(fp) : "memory");
      ok = (v >= tgt);
    }
    if (__ballot(ok) == ~0ull) break;
    __builtin_amdgcn_s_sleep(1);
    if (++guard > 30000) break;   // fail visibly, never hang the harness
  }
}
// tail prefetch of this lane's flag (no wait; drained by next loop-top VMCNT0)
__device__ inline void preflag_issue(const unsigned* f0, const unsigned* f1, unsigned* dst) {
  const int lane = threadIdx.x & 63;
  if (lane < 32) {
    const unsigned* fp = (lane < 16) ? (f0 + lane) : (f1 + (lane - 16));
    asm volatile("global_load_dword %0, %1, off sc0 sc1" : "=v"(*dst) : "v"(fp) : "memory");
  }
}

__global__ void k_init(unsigned* __restrict__ p, int n) {
  int i = blockIdx.x * 256 + threadIdx.x;
  if (i < n) p[i] = 0u;
}

// ---- CW = C @ W_ax.T  (M=32000, N=512, K=256), bf16 out ----
__global__ void __launch_bounds__(256) k_cw(const float* __restrict__ C,
                                            const float* __restrict__ Wax,
                                            unsigned short* __restrict__ CW) {
  const int tid = threadIdx.x, lane = tid & 63, wv = tid >> 6;
  const int l15 = lane & 15, l4 = lane >> 4;
  const int row = blockIdx.x * 64 + wv * 16 + l15;
  bf16x8 a[8];
  const float* crow = C + (size_t)row * EMB;
#pragma unroll
  for (int s = 0; s < 8; ++s) {
    const f32x4* p = (const f32x4*)(crow + s * 32 + l4 * 8);
    a[s] = cvt8(p[0], p[1]);
  }
  const int row_o_base = blockIdx.x * 64 + wv * 16 + l4 * 4;
  for (int ct = 0; ct < 8; ++ct) {
    f32x4 acc[4];
#pragma unroll
    for (int nf = 0; nf < 4; ++nf) acc[nf] = (f32x4){0.f, 0.f, 0.f, 0.f};
#pragma unroll
    for (int s = 0; s < 8; ++s) {
#pragma unroll
      for (int nf = 0; nf < 4; ++nf) {
        int col = ct * 64 + nf * 16 + l15;
        const f32x4* bp = (const f32x4*)(Wax + (size_t)col * EMB + s * 32 + l4 * 8);
        bf16x8 b = cvt8(bp[0], bp[1]);
        acc[nf] = mfma16(a[s], b, acc[nf]);
      }
    }
#pragma unroll
    for (int nf = 0; nf < 4; ++nf) {
      int col = ct * 64 + nf * 16 + l15;
#pragma unroll
      for (int r = 0; r < 4; ++r)
        CW[(size_t)(row_o_base + r) * HID + col] = (unsigned short)f2bf(acc[nf][r]);
    }
  }
}

// ---- the recurrent scan ----
__global__ void __launch_bounds__(256, 1) k_scan(
    const int* __restrict__ X, const float* __restrict__ Waa, const float* __restrict__ Wal,
    const float* __restrict__ ba, const unsigned short* __restrict__ CW,
    unsigned short* __restrict__ h0buf, unsigned short* __restrict__ h1buf,
    unsigned* __restrict__ flags) {
  extern __shared__ unsigned short lds[];
  unsigned short* ldsWaa = lds;                 // [64][512] bf16, 16B-unit swizzled
  unsigned short* ldsWal = lds + 64 * 512;
  unsigned short* packb  = lds + 2 * 64 * 512;  // 4 waves x 512 shorts (private)
  const int tid = threadIdx.x, lane = tid & 63, wv = tid >> 6;
  const int l15 = lane & 15, l4 = lane >> 4;
  const int g = blockIdx.x & 7, mem = blockIdx.x >> 3;
  const int colslice = mem * 64;
  unsigned* fl = flags + g * 64;
  unsigned* f0 = fl;           // 16 flags: h0 (2 per member)
  unsigned* f1 = fl + 16;      // 16 flags: h1

  // stage weight slices f32 -> bf16 LDS, 16B-unit swizzled
  for (int c = tid; c < 64 * 64; c += 256) {
    int row = c >> 6, u = c & 63, us = u ^ (row & 7);
    {
      const f32x4* p = (const f32x4*)(Waa + (size_t)(colslice + row) * HID + u * 8);
      *(bf16x8*)(ldsWaa + row * 512 + us * 8) = cvt8(p[0], p[1]);
    }
    {
      const f32x4* p = (const f32x4*)(Wal + (size_t)(colslice + row) * HID + u * 8);
      *(bf16x8*)(ldsWal + row * 512 + us * 8) = cvt8(p[0], p[1]);
    }
  }

  // per-wave geometry: each wave owns 2 col-tiles (32 cols)
  const int cb  = (wv & 1) * 2;                  // col-tile base within slice
  const int jc0 = colslice + cb * 16 + l15;      // out col, chain 0
  const int jc1 = jc0 + 16;                      // out col, chain 1
  const float ba0 = ba[jc0], ba1 = ba[jc1];
  const int wb0 = (cb * 16 + l15) * 512;         // LDS weight row base
  const int wb1 = wb0 + 16 * 512;
  const int swz = l15 & 7;
  const int aoff = l4 * 128 + l15 * 8;           // A-frag lane offset (shorts)
  // per-wave LDS pack region + offsets
  unsigned short* pk = packb + wv * 512;
  const int pl0 = ((l15 >> 3) + 0) * 128 + (l4 * 4) * 8 + (l15 & 7);
  const int pl1 = ((l15 >> 3) + 2) * 128 + (l4 * 4) * 8 + (l15 & 7);
  const int stbase = mem * 1024 + cb * 256 + lane * 8;  // wave's contiguous 1KB region
  const int brow = g * 16 + l4 * 4;
  unsigned short* h0g = h0buf + (size_t)g * (NSLOT * SLOT);
  unsigned short* h1g = h1buf + (size_t)g * (NSLOT * SLOT);
  __syncthreads();

#define WFRAG(W, wb, s) (*(const bf16x8*)((W) + (wb) + ((((s) * 4 + l4) ^ swz) * 8)))
#define LOAD16(arr, base)                                                         \
  _Pragma("unroll") for (int s = 0; s < 16; ++s)                                  \
    asm volatile("global_load_dwordx4 %0, %1, off sc0 sc1"                        \
                 : "=v"(arr[s]) : "v"((base) + s * 1024) : "memory");

  if (wv < 2) {
    // ================= h0 producers (waves 0,1) =================
    unsigned* myf = f0 + 2 * mem + (wv & 1);
    int idxA[4];
    unsigned cw0[4], cw1[4];
    unsigned preflag = 0;
    { // prologue: idx(0) -> cw(0) gathers; then idx(1)
      int id0[4];
#pragma unroll
      for (int r = 0; r < 4; ++r)
        asm volatile("global_load_dword %0, %1, off"
                     : "=v"(id0[r]) : "v"(X + (size_t)(brow + r) * SEQ) : "memory");
      VMCNT0; SCHED0;
#pragma unroll
      for (int r = 0; r < 4; ++r) {
        const unsigned short* c0 = CW + (size_t)id0[r] * HID + jc0;
        asm volatile("global_load_ushort %0, %1, off" : "=v"(cw0[r]) : "v"(c0) : "memory");
        asm volatile("global_load_ushort %0, %1, off" : "=v"(cw1[r]) : "v"(c0 + 16) : "memory");
      }
#pragma unroll
      for (int r = 0; r < 4; ++r)
        asm volatile("global_load_dword %0, %1, off"
                     : "=v"(idxA[r]) : "v"(X + (size_t)(brow + r) * SEQ + 1) : "memory");
    }
    for (int t = 0; t < SEQ; ++t) {
      VMCNT0; SCHED0;   // drain cw/idx/preflag prefetches before use
      poll2p(f0, f1, (unsigned)t, (unsigned)(t >= 2 ? t - 2 : 0), preflag);
      bf16x8 a0[16];
      const char* pa0 = (const char*)(h0g + ((t + 3) & 3) * SLOT + aoff);
      LOAD16(a0, pa0)
      VMCNT0; SCHED0;
      f32x4 acc0 = (f32x4){0.f, 0.f, 0.f, 0.f};
      f32x4 acc1 = (f32x4){0.f, 0.f, 0.f, 0.f};
#pragma unroll
      for (int s = 0; s < 16; ++s) {
        bf16x8 a = a0[s];
        acc0 = mfma16(a, WFRAG(ldsWaa, wb0, s), acc0);
        acc1 = mfma16(a, WFRAG(ldsWaa, wb1, s), acc1);
      }
#pragma unroll
      for (int r = 0; r < 4; ++r) {
        float v0 = fast_tanh(acc0[r] + bf2f((unsigned short)cw0[r]) + ba0);
        float v1 = fast_tanh(acc1[r] + bf2f((unsigned short)cw1[r]) + ba1);
        pk[pl0 + r * 8] = (unsigned short)f2bf(v0);
        pk[pl1 + r * 8] = (unsigned short)f2bf(v1);
      }
      LGKM0; SCHED0;                       // wave-private pack complete
      bf16x8 ov = *(const bf16x8*)(pk + lane * 8);
      st16(h0g + (t & 3) * SLOT + stbase, ov);
      VMCNT0;                              // store at coherent point
      if (lane == 0) sig(myf, (unsigned)(t + 1));
      // tail prefetches: cw(t+1) via idxA (=X(t+1), drained), idxA <- X(t+2), flags
#pragma unroll
      for (int r = 0; r < 4; ++r) {
        const unsigned short* c0 = CW + (size_t)idxA[r] * HID + jc0;
        asm volatile("global_load_ushort %0, %1, off" : "=v"(cw0[r]) : "v"(c0) : "memory");
        asm volatile("global_load_ushort %0, %1, off" : "=v"(cw1[r]) : "v"(c0 + 16) : "memory");
      }
      const int tp = (t + 2 < SEQ) ? t + 2 : SEQ - 1;
#pragma unroll
      for (int r = 0; r < 4; ++r)
        asm volatile("global_load_dword %0, %1, off"
                     : "=v"(idxA[r]) : "v"(X + (size_t)(brow + r) * SEQ + tp) : "memory");
      preflag_issue(f0, f1, &preflag);
    }
  } else {
    // ================= h1 producers (waves 2,3): step t computes h1(t-1) =========
    unsigned* myf = f1 + 2 * mem + (wv & 1);
    unsigned preflag = 0;
    for (int t = 0; t <= SEQ; ++t) {
      VMCNT0; SCHED0;   // drain preflag prefetch before use
      poll2p(f0, f1, (unsigned)t, (unsigned)t, preflag);
      if (t >= 1) {
        bf16x8 a1[16], a2[16];
        const char* pa1 = (const char*)(h0g + ((t + 3) & 3) * SLOT + aoff);  // h0(t-1)
        const char* pa2 = (const char*)(h1g + ((t + 2) & 3) * SLOT + aoff);  // h1(t-2)
        LOAD16(a1, pa1)
        LOAD16(a2, pa2)
        VMCNT16; SCHED0;                   // a1 ready
        f32x4 acc0 = (f32x4){0.f, 0.f, 0.f, 0.f};
        f32x4 acc1 = (f32x4){0.f, 0.f, 0.f, 0.f};
#pragma unroll
        for (int s = 0; s < 16; ++s) {
          bf16x8 a = a1[s];
          acc0 = mfma16(a, WFRAG(ldsWal, wb0, s), acc0);
          acc1 = mfma16(a, WFRAG(ldsWal, wb1, s), acc1);
        }
        VMCNT0; SCHED0;                    // a2 ready
#pragma unroll
        for (int s = 0; s < 16; ++s) {
          bf16x8 a = a2[s];
          acc0 = mfma16(a, WFRAG(ldsWaa, wb0, s), acc0);
          acc1 = mfma16(a, WFRAG(ldsWaa, wb1, s), acc1);
        }
#pragma unroll
        for (int r = 0; r < 4; ++r) {
          float v0 = fast_tanh(acc0[r] + ba0);
          float v1 = fast_tanh(acc1[r] + ba1);
          pk[pl0 + r * 8] = (unsigned short)f2bf(v0);
          pk[pl1 + r * 8] = (unsigned short)f2bf(v1);
        }
        LGKM0; SCHED0;
        bf16x8 ov = *(const bf16x8*)(pk + lane * 8);
        st16(h1g + ((t + 3) & 3) * SLOT + stbase, ov);   // h1(t-1) -> slot (t-1)%4
        VMCNT0;
      }
      if (lane == 0) sig(myf, (unsigned)(t + 1));
      preflag_issue(f0, f1, &preflag);
    }
  }
#undef LOAD16
#undef WFRAG
}

// ---- out = h1_final @ W_out.T + b_out  (M=128, N=32000, K=512) ----
__global__ void __launch_bounds__(256) k_out(const float* __restrict__ Wout,
                                             const float* __restrict__ bout,
                                             const unsigned short* __restrict__ h1buf,
                                             float* __restrict__ out) {
  const int tid = threadIdx.x, lane = tid & 63, wv = tid >> 6;
  const int l15 = lane & 15, l4 = lane >> 4;
  const int col = blockIdx.x * 64 + wv * 16 + l15;
  const float bo = bout[col];
  f32x4 acc[8];
#pragma unroll
  for (int rt = 0; rt < 8; ++rt) acc[rt] = (f32x4){0.f, 0.f, 0.f, 0.f};
  const int aoff = l4 * 128 + l15 * 8;
#pragma unroll 4
  for (int s = 0; s < 16; ++s) {
    const f32x4* bp = (const f32x4*)(Wout + (size_t)col * HID + s * 32 + l4 * 8);
    bf16x8 b = cvt8(bp[0], bp[1]);
#pragma unroll
    for (int rt = 0; rt < 8; ++rt) {
      // group rt, slot 3 (= 511 % 4) holds final h1(511)
      const unsigned short* ap = h1buf + (size_t)rt * (NSLOT * SLOT) + 3 * SLOT + aoff + s * 512;
      acc[rt] = mfma16(*(const bf16x8*)ap, b, acc[rt]);
    }
  }
#pragma unroll
  for (int rt = 0; rt < 8; ++rt) {
#pragma unroll
    for (int r = 0; r < 4; ++r) {
      int row = rt * 16 + l4 * 4 + r;
      out[(size_t)row * VOCAB + col] = acc[rt][r] + bo;
    }
  }
}

extern "C" void kernel_launch(void* const* d_in, const int* in_sizes, int n_in,
                              void* d_out, int out_size, void* d_ws, size_t ws_size,
                              hipStream_t stream) {
  const int*   X    = (const int*)d_in[0];
  const float* C    = (const float*)d_in[1];
  const float* Wax  = (const float*)d_in[2];
  const float* Waa  = (const float*)d_in[3];
  const float* Wal  = (const float*)d_in[4];
  const float* ba   = (const float*)d_in[5];
  const float* Wout = (const float*)d_in[6];
  const float* bout = (const float*)d_in[7];
  float* out = (float*)d_out;
  char* ws = (char*)d_ws;
  (void)in_sizes; (void)n_in; (void)out_size;

  const size_t cw_bytes = (size_t)VOCAB * HID * 2;          // 32,768,000
  const size_t h_bytes  = 8ull * NSLOT * SLOT * 2;          // 524,288 per tensor
  const size_t off_h0 = cw_bytes;
  const size_t off_h1 = off_h0 + h_bytes;
  const size_t off_fl = off_h1 + h_bytes;
  const size_t fl_bytes = 8 * 64 * 4;                       // 2 KB
  if (ws_size < off_fl + fl_bytes) return;

  unsigned short* CWp = (unsigned short*)(ws);
  unsigned short* h0  = (unsigned short*)(ws + off_h0);
  unsigned short* h1  = (unsigned short*)(ws + off_h1);
  unsigned*       fl  = (unsigned*)(ws + off_fl);

  const int zero_words = (int)((2 * h_bytes + fl_bytes) / 4);
  hipLaunchKernelGGL(k_init, dim3((zero_words + 255) / 256), dim3(256), 0, stream,
                     (unsigned*)(ws + off_h0), zero_words);
  hipLaunchKernelGGL(k_cw, dim3(VOCAB / 64), dim3(256), 0, stream, C, Wax, CWp);
  hipFuncSetAttribute((const void*)k_scan, hipFuncAttributeMaxDynamicSharedMemorySize, 135168);
  hipLaunchKernelGGL(k_scan, dim3(64), dim3(256), 135168, stream,
                     X, Waa, Wal, ba, CWp, h0, h1, fl);
  hipLaunchKernelGGL(k_out, dim3(VOCAB / 64), dim3(256), 0, stream, Wout, bout, h1, out);
}